// Round 1
// baseline (98.137 us; speedup 1.0000x reference)
//
#include <hip/hip_runtime.h>

#define INF_VAL 100000000.0f
#define NUM_ANN 512
#define TOTAL_PTS 126976

__global__ __launch_bounds__(256) void assign_levels_kernel(
    const float* __restrict__ ann,   // [512][3] l, r, cls
    const float* __restrict__ a1,
    const float* __restrict__ a2,
    const float* __restrict__ a3,
    const float* __restrict__ a4,
    const float* __restrict__ a5,
    float* __restrict__ out)         // [126976][12]
{
    __shared__ float4 s_ann[NUM_ANN];   // x=l, y=r, z=radius, w=area
    __shared__ float  s_cls[NUM_ANN];

    const int tid = threadIdx.x;
    for (int k = tid; k < NUM_ANN; k += 256) {
        float l = ann[k * 3 + 0];
        float r = ann[k * 3 + 1];
        float c = ann[k * 3 + 2];
        // radius = 4.5 if cls==0 else 0, plus 1.5 if cls==1 else 0
        float radius = (c == 0.0f ? 4.5f : 0.0f) + (c == 1.0f ? 1.5f : 0.0f);
        s_ann[k] = make_float4(l, r, radius, r - l);
        s_cls[k] = c;
    }
    __syncthreads();

    const int g = blockIdx.x * 256 + tid;
    if (g >= TOTAL_PTS) return;

    // level boundaries: sizes 65536, 32768, 16384, 8192, 4096
    int lvl, base;
    const float* anchors;
    float lo, hi;
    // lo/hi = SIZES[i] * (22050/128) computed in double, cast to f32 (JAX semantics)
    if (g < 65536) {
        lvl = 0; base = 0; anchors = a1;
        lo = (float)(-1.0 * 172.265625);
        hi = (float)(0.45608904 * 172.265625);
    } else if (g < 98304) {
        lvl = 1; base = 65536; anchors = a2;
        lo = (float)(0.45608904 * 172.265625);
        hi = (float)(0.878505635 * 172.265625);
    } else if (g < 114688) {
        lvl = 2; base = 98304; anchors = a3;
        lo = (float)(0.878505635 * 172.265625);
        hi = (float)(1.557724045 * 172.265625);
    } else if (g < 122880) {
        lvl = 3; base = 114688; anchors = a4;
        lo = (float)(1.557724045 * 172.265625);
        hi = (float)(2.264785525 * 172.265625);
    } else {
        lvl = 4; base = 122880; anchors = a5;
        lo = (float)(2.264785525 * 172.265625);
        hi = (float)(1000.0 * 172.265625);
    }

    const float stride = (float)(2 << lvl);        // 2^(lvl+1)
    const float p = anchors[g - base];

    float best = INF_VAL;
    int amin = 0;

    #pragma unroll 4
    for (int k = 0; k < NUM_ANN; ++k) {
        float4 a = s_ann[k];                        // broadcast LDS read
        // limit = l + radius*stride (radius*stride exact: {1.5,4.5} * 2^k)
        float limit = __fadd_rn(a.x, __fmul_rn(a.z, stride));
        float l_star = p - a.x;
        float r_star = a.y - p;
        float max_lr = fmaxf(l_star, r_star);
        bool in_radii = (p >= a.x) && (p <= fminf(a.y, limit));
        bool in_range = (max_lr >= lo) && (max_lr <= hi);
        float area = (in_radii && in_range) ? a.w : INF_VAL;
        if (area < best) { best = area; amin = k; } // strict <: first-min (jnp.argmin)
    }

    const float4 aw = s_ann[amin];
    const float cls_raw = s_cls[amin];
    const float cls_out = (best == INF_VAL) ? 0.0f : cls_raw;
    const float inv_stride = 1.0f / stride;        // exact (pow2)
    const float ls = p - aw.x;
    const float rs = aw.y - p;

    float4 o0 = make_float4(amin != 0 ? 1.0f : 0.0f, aw.x, aw.y, cls_out);
    float4 o1 = make_float4(aw.x * inv_stride, aw.y * inv_stride, cls_out, ls);
    float4 o2 = make_float4(rs, ls * inv_stride, rs * inv_stride, (float)(lvl + 1));

    float4* orow = (float4*)(out + (size_t)g * 12);
    orow[0] = o0;
    orow[1] = o1;
    orow[2] = o2;
}

extern "C" void kernel_launch(void* const* d_in, const int* in_sizes, int n_in,
                              void* d_out, int out_size, void* d_ws, size_t ws_size,
                              hipStream_t stream) {
    const float* ann = (const float*)d_in[0];
    const float* a1  = (const float*)d_in[1];
    const float* a2  = (const float*)d_in[2];
    const float* a3  = (const float*)d_in[3];
    const float* a4  = (const float*)d_in[4];
    const float* a5  = (const float*)d_in[5];
    float* out = (float*)d_out;

    const int blocks = (TOTAL_PTS + 255) / 256;    // 496
    assign_levels_kernel<<<blocks, 256, 0, stream>>>(ann, a1, a2, a3, a4, a5, out);
}

// Round 2
// 69.391 us; speedup vs baseline: 1.4143x; 1.4143x over previous
//
#include <hip/hip_runtime.h>

#define INF_VAL 100000000.0f
#define NUM_ANN 512
#define TOTAL_PTS 126976

__device__ __constant__ float c_lo[5] = {
    (float)(-1.0 * 172.265625),
    (float)(0.45608904 * 172.265625),
    (float)(0.878505635 * 172.265625),
    (float)(1.557724045 * 172.265625),
    (float)(2.264785525 * 172.265625)
};
__device__ __constant__ float c_hi[5] = {
    (float)(0.45608904 * 172.265625),
    (float)(0.878505635 * 172.265625),
    (float)(1.557724045 * 172.265625),
    (float)(2.264785525 * 172.265625),
    (float)(1000.0 * 172.265625)
};
__device__ __constant__ int c_n[5]    = {65536, 32768, 16384, 8192, 4096};
__device__ __constant__ int c_base[5] = {0, 65536, 98304, 114688, 122880};

// ws[g] = (float_bits(min_area) << 32) | argmin_index.
// Positive-float bits are monotonic as u32, so u64 min == lexicographic
// (area, index) min == jnp.argmin first-occurrence tie-break.
__global__ __launch_bounds__(256) void init_kernel(unsigned long long* __restrict__ ws) {
    int g = blockIdx.x * 256 + threadIdx.x;
    if (g < TOTAL_PTS)
        ws[g] = ((unsigned long long)__float_as_uint(INF_VAL)) << 32;  // (INF, amin=0)
}

__global__ __launch_bounds__(256) void scatter_kernel(const float* __restrict__ ann,
                                                      unsigned long long* __restrict__ ws) {
    int t = blockIdx.x * 256 + threadIdx.x;
    if (t >= NUM_ANN * 5) return;
    int k   = t & (NUM_ANN - 1);
    int lvl = t >> 9;

    float l = ann[k * 3 + 0];
    float r = ann[k * 3 + 1];
    float c = ann[k * 3 + 2];

    float stride = (float)(2 << lvl);                 // 2^(lvl+1)
    float radius = (c == 0.0f ? 4.5f : 0.0f) + (c == 1.0f ? 1.5f : 0.0f);
    float limit  = __fadd_rn(l, __fmul_rn(radius, stride));  // same f32 ops as ref
    float U      = fminf(r, limit);
    float lo     = c_lo[lvl];
    float hi     = c_hi[lvl];
    float area   = r - l;
    int   n      = c_n[lvl];
    int   pbase  = c_base[lvl];

    // Conservative anchor-index window (widened; each j re-checked exactly).
    // p = (j+0.5)*stride in [l, U]  ->  j in [l/stride-0.5, U/stride-0.5]
    int j0 = (int)floorf(l / stride - 0.5f) - 1;
    int j1 = (int)ceilf (U / stride - 0.5f) + 1;
    j0 = j0 < 0 ? 0 : j0;
    j1 = j1 > n - 1 ? n - 1 : j1;

    unsigned long long key =
        (((unsigned long long)__float_as_uint(area)) << 32) | (unsigned)k;

    for (int j = j0; j <= j1; ++j) {
        float p      = (j + 0.5f) * stride;           // exact, == anchors[j]
        float l_star = p - l;
        float r_star = r - p;
        float max_lr = fmaxf(l_star, r_star);
        bool in_radii = (p >= l) && (p <= U);
        bool in_range = (max_lr >= lo) && (max_lr <= hi);
        if (in_radii && in_range)
            atomicMin(&ws[pbase + j], key);
    }
}

__global__ __launch_bounds__(256) void gather_kernel(const float* __restrict__ ann,
                                                     const unsigned long long* __restrict__ ws,
                                                     float* __restrict__ out) {
    int g = blockIdx.x * 256 + threadIdx.x;
    if (g >= TOTAL_PTS) return;

    int lvl, base;
    if      (g <  65536) { lvl = 0; base = 0;      }
    else if (g <  98304) { lvl = 1; base = 65536;  }
    else if (g < 114688) { lvl = 2; base = 98304;  }
    else if (g < 122880) { lvl = 3; base = 114688; }
    else                 { lvl = 4; base = 122880; }

    float stride = (float)(2 << lvl);
    float p = ((g - base) + 0.5f) * stride;           // exact, == anchors input

    unsigned long long key = ws[g];
    unsigned k        = (unsigned)(key & 0xffffffffu);
    unsigned areaBits = (unsigned)(key >> 32);

    float l = ann[k * 3 + 0];                         // <=512 rows, L1-resident
    float r = ann[k * 3 + 1];
    float c = ann[k * 3 + 2];
    float cls_out = (areaBits == __float_as_uint(INF_VAL)) ? 0.0f : c;

    float inv = 1.0f / stride;                        // pow2: exact
    float ls = p - l;
    float rs = r - p;

    float4 o0 = make_float4(k != 0 ? 1.0f : 0.0f, l, r, cls_out);
    float4 o1 = make_float4(l * inv, r * inv, cls_out, ls);
    float4 o2 = make_float4(rs, ls * inv, rs * inv, (float)(lvl + 1));

    float4* orow = (float4*)(out + (size_t)g * 12);
    orow[0] = o0;
    orow[1] = o1;
    orow[2] = o2;
}

extern "C" void kernel_launch(void* const* d_in, const int* in_sizes, int n_in,
                              void* d_out, int out_size, void* d_ws, size_t ws_size,
                              hipStream_t stream) {
    const float* ann = (const float*)d_in[0];
    float* out = (float*)d_out;
    unsigned long long* ws = (unsigned long long*)d_ws;  // 126976 * 8 B ~= 1 MB

    const int blocks_pts = (TOTAL_PTS + 255) / 256;      // 496
    const int blocks_sc  = (NUM_ANN * 5 + 255) / 256;    // 10

    init_kernel   <<<blocks_pts, 256, 0, stream>>>(ws);
    scatter_kernel<<<blocks_sc,  256, 0, stream>>>(ann, ws);
    gather_kernel <<<blocks_pts, 256, 0, stream>>>(ann, ws, out);
}

// Round 3
// 66.455 us; speedup vs baseline: 1.4767x; 1.0442x over previous
//
#include <hip/hip_runtime.h>

#define INF_VAL 100000000.0f
#define NUM_ANN 512
#define TOTAL_PTS 126976

// lo/hi = SIZES[i] * (22050/128), computed in double then cast (JAX promotion)
__device__ __constant__ float c_lo[5] = {
    (float)(-1.0 * 172.265625),
    (float)(0.45608904 * 172.265625),
    (float)(0.878505635 * 172.265625),
    (float)(1.557724045 * 172.265625),
    (float)(2.264785525 * 172.265625)
};
__device__ __constant__ float c_hi[5] = {
    (float)(0.45608904 * 172.265625),
    (float)(0.878505635 * 172.265625),
    (float)(1.557724045 * 172.265625),
    (float)(2.264785525 * 172.265625),
    (float)(1000.0 * 172.265625)
};

__global__ __launch_bounds__(256) void assign_compact_kernel(
    const float* __restrict__ ann,   // [512][3] l(sorted asc), r, cls
    float* __restrict__ out)         // [126976][12]
{
    __shared__ float s_l[NUM_ANN];
    __shared__ float s_r[NUM_ANN];
    __shared__ float s_c[NUM_ANN];

    const int tid = threadIdx.x;
    for (int k = tid; k < NUM_ANN; k += 256) {
        s_l[k] = ann[k * 3 + 0];
        s_r[k] = ann[k * 3 + 1];
        s_c[k] = ann[k * 3 + 2];
    }
    __syncthreads();

    const int g = blockIdx.x * 256 + tid;   // grid covers exactly 126976

    int lvl, base;
    if      (g <  65536) { lvl = 0; base = 0;      }
    else if (g <  98304) { lvl = 1; base = 65536;  }
    else if (g < 114688) { lvl = 2; base = 98304;  }
    else if (g < 122880) { lvl = 3; base = 114688; }
    else                 { lvl = 4; base = 122880; }

    const float stride = (float)(2 << lvl);            // 2^(lvl+1)
    const float p  = ((g - base) + 0.5f) * stride;     // exact == anchors input
    const float lo = c_lo[lvl];
    const float hi = c_hi[lvl];

    // Candidate window on l: l in [p - 4.5*stride, p]  (max radius = 4.5).
    // Widen by 1.0f (>> max 0.5 ulp rounding of limit at |x|<=131072, ulp~0.008);
    // every candidate is re-verified with the exact reference predicate below.
    const float wlo = p - 4.5f * stride - 1.0f;

    // Binary search: first index with s_l[idx] >= wlo   (s_l sorted ascending)
    int idx = 0;
    {
        int n = NUM_ANN;
        while (n > 1) {
            int half = n >> 1;
            idx += (s_l[idx + half - 1] < wlo) ? half : 0;
            n -= half;
        }
        if (s_l[idx] < wlo) idx = NUM_ANN;  // all elements < wlo
    }

    float best = INF_VAL;
    int amin = 0;

    for (int k = idx; k < NUM_ANN; ++k) {
        float l = s_l[k];
        if (l > p) break;                   // sorted: no further candidates
        float r = s_r[k];
        float c = s_c[k];
        float radius = (c == 0.0f ? 4.5f : 0.0f) + (c == 1.0f ? 1.5f : 0.0f);
        float limit  = __fadd_rn(l, __fmul_rn(radius, stride)); // exact ref ops
        float l_star = p - l;
        float r_star = r - p;
        float max_lr = fmaxf(l_star, r_star);
        bool in_radii = (p >= l) && (p <= fminf(r, limit));
        bool in_range = (max_lr >= lo) && (max_lr <= hi);
        float area = (in_radii && in_range) ? (r - l) : INF_VAL;
        if (area < best) { best = area; amin = k; }  // strict <: first-occurrence
    }

    const float l = s_l[amin];
    const float r = s_r[amin];
    const float cls_out = (best == INF_VAL) ? 0.0f : s_c[amin];
    const float inv = 1.0f / stride;                  // pow2: exact
    const float ls = p - l;
    const float rs = r - p;

    float4 o0 = make_float4(amin != 0 ? 1.0f : 0.0f, l, r, cls_out);
    float4 o1 = make_float4(l * inv, r * inv, cls_out, ls);
    float4 o2 = make_float4(rs, ls * inv, rs * inv, (float)(lvl + 1));

    float4* orow = (float4*)(out + (size_t)g * 12);
    orow[0] = o0;
    orow[1] = o1;
    orow[2] = o2;
}

extern "C" void kernel_launch(void* const* d_in, const int* in_sizes, int n_in,
                              void* d_out, int out_size, void* d_ws, size_t ws_size,
                              hipStream_t stream) {
    const float* ann = (const float*)d_in[0];
    float* out = (float*)d_out;
    assign_compact_kernel<<<TOTAL_PTS / 256, 256, 0, stream>>>(ann, out);
}